// Round 3
// baseline (328.347 us; speedup 1.0000x reference)
//
#include <hip/hip_runtime.h>

#define TT 16384      // total tokens
#define DD 2048       // d_model
#define EE 64         // experts
#define TM 64         // tokens per block
#define NBLK (TT/TM)  // 256
#define CAP 512u      // expert capacity (keep if 1-based position < CAP)
#define XSTR 67       // Xs row stride (odd -> conflict-free lane reads)

__device__ __forceinline__ bool pair_gt(float va, int ia, float vb, int ib) {
    // jax.lax.top_k ordering: higher value wins; tie -> lower index wins
    return (va > vb) || (va == vb && ia < ib);
}

// k1: fused gate GEMM (f32, deterministic) + softmax + top2 + per-block stats.
// 1024 threads = 16 waves = 8 expert-octets x 2 K-halves. lane = token.
// W via wave-uniform s_load (SGPR operand of v_fmac); X via double-buffered
// LDS tile Xs[2][64][67], 1 barrier per 32-wide K-step.
__global__ __launch_bounds__(1024) void k1_router(
    const float* __restrict__ X, const float* __restrict__ W,
    const float* __restrict__ bias,
    uint4* __restrict__ top2, unsigned* __restrict__ counts,
    float* __restrict__ probsum, float* __restrict__ zsum)
{
    __shared__ float Xs[2][TM][XSTR];  // [buf][token][khalf*33 + kc]
    __shared__ float Ls[TM][68];       // logits [token][expert] (68: 16B rows)
    __shared__ float lseS[TM];
    __shared__ float ps2[16][EE];
    __shared__ unsigned cnt[EE];

    const int tid = threadIdx.x;
    const int b = blockIdx.x;
    const int tok0 = b * TM;
    const int w = tid >> 6;                    // wave 0..15
    const int lane = tid & 63;                 // token
    const int kg = w >> 3;                     // K-half 0/1 (wave-uniform)
    const int we0 = __builtin_amdgcn_readfirstlane((w & 7) * 8); // expert base
    const int xoff = __builtin_amdgcn_readfirstlane(kg * 33);

    // staging map: thread -> (token row sr, K-half sg, 4-float chunk sc)
    const int sr = tid >> 4;
    const int sidx = tid & 15;
    const int sg = sidx >> 3;
    const int sc = (sidx & 7) * 4;
    const int sdst = sg * 33 + sc;
    const float* gX = X + (size_t)(tok0 + sr) * DD + sg * 1024 + sc;

    const float* Wb = W + (size_t)we0 * DD + kg * 1024; // uniform -> s_load

    float acc[8] = {0.f,0.f,0.f,0.f,0.f,0.f,0.f,0.f};

    // prologue: stage tile 0, prefetch tile 1
    float4 xr = *(const float4*)(gX);
    Xs[0][sr][sdst+0] = xr.x; Xs[0][sr][sdst+1] = xr.y;
    Xs[0][sr][sdst+2] = xr.z; Xs[0][sr][sdst+3] = xr.w;
    xr = *(const float4*)(gX + 32);
    __syncthreads();

    for (int s = 0; s < 32; ++s) {
        if (s + 1 < 32) {
            const int nb = (s + 1) & 1;
            Xs[nb][sr][sdst+0] = xr.x; Xs[nb][sr][sdst+1] = xr.y;
            Xs[nb][sr][sdst+2] = xr.z; Xs[nb][sr][sdst+3] = xr.w;
            if (s + 2 < 32) xr = *(const float4*)(gX + (s + 2) * 32);
        }
        const float* xrow = &Xs[s & 1][lane][xoff];
        const float* Wk = Wb + s * 32;
        #pragma unroll
        for (int kc = 0; kc < 32; kc += 4) {
            float4 wv[8];
            #pragma unroll
            for (int e = 0; e < 8; ++e)
                wv[e] = *(const float4*)(Wk + e * DD + kc);   // s_load_dwordx4
            const float x0 = xrow[kc + 0];
            const float x1 = xrow[kc + 1];
            const float x2 = xrow[kc + 2];
            const float x3 = xrow[kc + 3];
            #pragma unroll
            for (int e = 0; e < 8; ++e) {
                acc[e] = fmaf(x0, wv[e].x, acc[e]);
                acc[e] = fmaf(x1, wv[e].y, acc[e]);
                acc[e] = fmaf(x2, wv[e].z, acc[e]);
                acc[e] = fmaf(x3, wv[e].w, acc[e]);
            }
        }
        __syncthreads();
    }

    // combine K-halves in fixed order (g0 chain + g1 chain), add bias
    if (tid < EE) cnt[tid] = 0;
    if (kg == 1) {
        *(float4*)&Ls[lane][we0 + 0] = make_float4(acc[0], acc[1], acc[2], acc[3]);
        *(float4*)&Ls[lane][we0 + 4] = make_float4(acc[4], acc[5], acc[6], acc[7]);
    }
    __syncthreads();
    if (kg == 0) {
        const float4 p0 = *(const float4*)&Ls[lane][we0 + 0];
        const float4 p1 = *(const float4*)&Ls[lane][we0 + 4];
        float f[8];
        f[0]=acc[0]+p0.x; f[1]=acc[1]+p0.y; f[2]=acc[2]+p0.z; f[3]=acc[3]+p0.w;
        f[4]=acc[4]+p1.x; f[5]=acc[5]+p1.y; f[6]=acc[6]+p1.z; f[7]=acc[7]+p1.w;
        #pragma unroll
        for (int e = 0; e < 8; ++e) f[e] += bias[we0 + e];
        *(float4*)&Ls[lane][we0 + 0] = make_float4(f[0], f[1], f[2], f[3]);
        *(float4*)&Ls[lane][we0 + 4] = make_float4(f[4], f[5], f[6], f[7]);
    }
    __syncthreads();

    // epilogue: 16 threads per token, 4 experts each
    const int tok = tid >> 4;
    const int o = tid & 15;
    const float4 vv = *(const float4*)&Ls[tok][o * 4];
    float v[4] = {vv.x, vv.y, vv.z, vv.w};

    float mx = fmaxf(fmaxf(v[0], v[1]), fmaxf(v[2], v[3]));
    #pragma unroll
    for (int sft = 1; sft < 16; sft <<= 1) mx = fmaxf(mx, __shfl_xor(mx, sft, 64));
    float sum = 0.f;
    #pragma unroll
    for (int j = 0; j < 4; ++j) sum += expf(v[j] - mx);
    #pragma unroll
    for (int sft = 1; sft < 16; sft <<= 1) sum += __shfl_xor(sum, sft, 64);
    const float lse = mx + logf(sum);

    float v1 = v[0]; int i1 = o * 4;
    float v2 = -3.402823466e38f; int i2 = 0x7fffffff;
    #pragma unroll
    for (int j = 1; j < 4; ++j) {
        const float vvj = v[j]; const int e = o * 4 + j;
        if (pair_gt(vvj, e, v1, i1)) { v2 = v1; i2 = i1; v1 = vvj; i1 = e; }
        else if (pair_gt(vvj, e, v2, i2)) { v2 = vvj; i2 = e; }
    }
    #pragma unroll
    for (int sft = 1; sft < 16; sft <<= 1) {
        const float ov1 = __shfl_xor(v1, sft, 64); const int oi1 = __shfl_xor(i1, sft, 64);
        const float ov2 = __shfl_xor(v2, sft, 64); const int oi2 = __shfl_xor(i2, sft, 64);
        if (pair_gt(ov1, oi1, v1, i1)) {
            if (pair_gt(v1, i1, ov2, oi2)) { v2 = v1; i2 = i1; }
            else                            { v2 = ov2; i2 = oi2; }
            v1 = ov1; i1 = oi1;
        } else {
            if (pair_gt(ov1, oi1, v2, i2)) { v2 = ov1; i2 = oi1; }
        }
    }

    if (o == 0) {
        lseS[tok] = lse;
        top2[tok0 + tok] = make_uint4((unsigned)i1, (unsigned)i2,
                                      __float_as_uint(expf(v1 - lse)),
                                      __float_as_uint(expf(v2 - lse)));
        atomicAdd(&cnt[i1], 1u);
        atomicAdd(&cnt[i2], 1u);
    }
    __syncthreads();

    // per-expert prob sums, fixed-order partials
    {
        const int e = tid & 63;
        const int tp = tid >> 6;               // 16 groups x 4 tokens
        float sme = 0.f;
        for (int t = tp * 4; t < tp * 4 + 4; ++t)
            sme += expf(Ls[t][e] - lseS[t]);
        ps2[tp][e] = sme;
    }
    __syncthreads();
    if (tid < EE) {
        float sacc = 0.f;
        #pragma unroll
        for (int p = 0; p < 16; ++p) sacc += ps2[p][tid];
        probsum[b * EE + tid] = sacc;
        counts[b * EE + tid] = cnt[tid];
    }
    if (tid == 0) {
        float z = 0.f;
        for (int t = 0; t < TM; ++t) z += lseS[t] * lseS[t];
        zsum[b] = z;
    }
}

// k2: per-expert exclusive prefix over 256 chunks (2-pass) + loss
__global__ __launch_bounds__(256) void k2_scan(
    const unsigned* __restrict__ counts, const float* __restrict__ probsum,
    const float* __restrict__ zsum, unsigned* __restrict__ base,
    float* __restrict__ loss_out)
{
    __shared__ unsigned pc[4][EE];
    __shared__ float pps[4][EE];
    __shared__ float zz[256];
    const int tid = threadIdx.x;
    const int e = tid & 63, q = tid >> 6;
    const int b0 = q * (NBLK / 4), b1 = b0 + (NBLK / 4);

    unsigned csum = 0; float psum_ = 0.f;
    for (int bb = b0; bb < b1; ++bb) {
        csum += counts[bb * EE + e];
        psum_ += probsum[bb * EE + e];
    }
    pc[q][e] = csum; pps[q][e] = psum_;
    zz[tid] = zsum[tid];
    __syncthreads();

    unsigned off = 0;
    for (int qq = 0; qq < q; ++qq) off += pc[qq][e];
    unsigned run = off;
    for (int bb = b0; bb < b1; ++bb) {
        base[bb * EE + e] = run;
        run += counts[bb * EE + e];
    }

    if (q == 0) {
        const unsigned tot = pc[0][e] + pc[1][e] + pc[2][e] + pc[3][e];
        const float pt = pps[0][e] + pps[1][e] + pps[2][e] + pps[3][e];
        float a = (float)tot * pt;
        #pragma unroll
        for (int sft = 1; sft < 64; sft <<= 1) a += __shfl_xor(a, sft, 64);
        float z4 = zz[tid] + zz[tid + 64] + zz[tid + 128] + zz[tid + 192];
        #pragma unroll
        for (int sft = 1; sft < 64; sft <<= 1) z4 += __shfl_xor(z4, sft, 64);
        if (e == 0) {
            const float Tf = (float)TT;
            loss_out[0] = 0.01f * 64.0f * (a / (Tf * Tf)) + z4 / Tf;
        }
    }
}

// k3: capacity ranking within each 64-token chunk + dense mask/weight writes
__global__ __launch_bounds__(256) void k3_write(
    const uint4* __restrict__ top2, const unsigned* __restrict__ base,
    float* __restrict__ mask_out, float* __restrict__ w_out)
{
    __shared__ unsigned ti1[TM], ti2[TM], tk1[TM], tk2[TM];
    __shared__ float tw1[TM], tw2[TM];
    const int b = blockIdx.x, tid = threadIdx.x;
    if (tid < TM) {
        const uint4 v = top2[b * TM + tid];
        ti1[tid] = v.x; ti2[tid] = v.y;
        tw1[tid] = __uint_as_float(v.z); tw2[tid] = __uint_as_float(v.w);
    }
    __syncthreads();
    if (tid < EE) {
        const unsigned e = (unsigned)tid;
        unsigned cc = base[b * EE + tid];
        for (int i = 0; i < TM; ++i) {   // token order = global cumsum order
            if (ti1[i] == e) { cc++; tk1[i] = (cc < CAP); }
            if (ti2[i] == e) { cc++; tk2[i] = (cc < CAP); }
        }
    }
    __syncthreads();
    const int i = tid >> 2, q = tid & 3;
    const unsigned a1 = ti1[i], a2 = ti2[i];
    const unsigned kp1 = tk1[i], kp2 = tk2[i];
    const float w1 = tw1[i], w2 = tw2[i];
    float om[16], ow[16];
    #pragma unroll
    for (int j = 0; j < 16; ++j) {
        const unsigned e = (unsigned)(q * 16 + j);
        float mv = 0.f, wv = 0.f;
        if (e == a1 && kp1) { mv = 1.f; wv = w1; }
        if (e == a2 && kp2) { mv = 1.f; wv = w2; }
        om[j] = mv; ow[j] = wv;
    }
    float* mrow = mask_out + (size_t)(b * TM + i) * EE + q * 16;
    float* wrow = w_out    + (size_t)(b * TM + i) * EE + q * 16;
    #pragma unroll
    for (int j4 = 0; j4 < 4; ++j4) {
        *(float4*)(mrow + j4 * 4) = make_float4(om[j4*4+0], om[j4*4+1], om[j4*4+2], om[j4*4+3]);
        *(float4*)(wrow + j4 * 4) = make_float4(ow[j4*4+0], ow[j4*4+1], ow[j4*4+2], ow[j4*4+3]);
    }
}

extern "C" void kernel_launch(void* const* d_in, const int* in_sizes, int n_in,
                              void* d_out, int out_size, void* d_ws, size_t ws_size,
                              hipStream_t stream)
{
    const float* X    = (const float*)d_in[0];
    const float* W    = (const float*)d_in[1];
    const float* bias = (const float*)d_in[2];
    float* out = (float*)d_out;
    float* mask_out = out;
    float* w_out    = out + (size_t)TT * EE;
    float* loss_out = out + (size_t)2 * TT * EE;

    char* ws = (char*)d_ws;
    uint4*    top2    = (uint4*)ws;                               // 256 KB
    unsigned* counts  = (unsigned*)(ws + 262144);                 // 64 KB
    float*    probsum = (float*)(ws + 262144 + 65536);            // 64 KB
    float*    zsum    = (float*)(ws + 262144 + 131072);           // 1 KB (pad 4K)
    unsigned* base    = (unsigned*)(ws + 262144 + 131072 + 4096); // 64 KB

    k1_router<<<NBLK, 1024, 0, stream>>>(X, W, bias, top2, counts, probsum, zsum);
    k2_scan<<<1, 256, 0, stream>>>(counts, probsum, zsum, base, loss_out);
    k3_write<<<NBLK, 256, 0, stream>>>(top2, base, mask_out, w_out);
}

// Round 4
// 292.195 us; speedup vs baseline: 1.1237x; 1.1237x over previous
//
#include <hip/hip_runtime.h>

#define TT 16384      // total tokens
#define DD 2048       // d_model
#define EE 64         // experts
#define TM 64         // tokens per block
#define NBLK (TT/TM)  // 256
#define CAP 512u      // expert capacity (keep if 1-based position < CAP)
#define XSTR 67       // Xs row stride (odd -> conflict-free lane reads)

__device__ __forceinline__ bool pair_gt(float va, int ia, float vb, int ib) {
    // jax.lax.top_k ordering: higher value wins; tie -> lower index wins
    return (va > vb) || (va == vb && ia < ib);
}

// k1: fused gate GEMM (f32, deterministic) + softmax + top2 + per-block stats.
// 1024 threads = 16 waves = 8 expert-octets x 2 K-halves. lane = token.
// W via per-lane global_load_dwordx4 (same addr across lanes -> L1 broadcast;
// vmcnt-pipelined, 2-bank ping-pong). Address laundered through LDS so the
// compiler cannot scalarize it back to s_load (v2's stall: 8 s_loads +
// lgkmcnt(0) per 4k-group, ~200cy unhidden). X via double-buffered LDS tile.
__global__ __launch_bounds__(1024) void k1_router(
    const float* __restrict__ X, const float* __restrict__ W,
    const float* __restrict__ bias,
    uint4* __restrict__ top2, unsigned* __restrict__ counts,
    float* __restrict__ probsum, float* __restrict__ zsum)
{
    __shared__ float Xs[2][TM][XSTR];  // [buf][token][khalf*33 + kc]
    __shared__ float Ls[TM][68];       // logits [token][expert]
    __shared__ float lseS[TM];
    __shared__ float ps2[16][EE];
    __shared__ unsigned cnt[EE];
    __shared__ int zt[1];              // laundering zero (value opaque to compiler)

    const int tid = threadIdx.x;
    const int b = blockIdx.x;
    const int tok0 = b * TM;
    const int w = tid >> 6;                    // wave 0..15
    const int lane = tid & 63;                 // token
    const int kg = w >> 3;                     // K-half 0/1 (wave-uniform)
    const int we0 = (w & 7) * 8;               // expert base
    const int xoff = kg * 33;

    if (tid == 0) zt[0] = 0;

    // X staging map: thread -> (token row sr, K-half sg, 4-float chunk sc)
    const int sr = tid >> 4;
    const int sidx = tid & 15;
    const int sg = sidx >> 3;
    const int sc = (sidx & 7) * 4;
    const int sdst = sg * 33 + sc;
    const float* gX = X + (size_t)(tok0 + sr) * DD + sg * 1024 + sc;

    float acc[8] = {0.f,0.f,0.f,0.f,0.f,0.f,0.f,0.f};

    // prologue: stage tile 0, prefetch tile 1 (also covers the zt write)
    float4 xr = *(const float4*)(gX);
    Xs[0][sr][sdst+0] = xr.x; Xs[0][sr][sdst+1] = xr.y;
    Xs[0][sr][sdst+2] = xr.z; Xs[0][sr][sdst+3] = xr.w;
    xr = *(const float4*)(gX + 32);
    __syncthreads();

    const int lz = zt[0];                       // 0, but opaque -> VGPR addressing
    const float* Wb = W + (size_t)(we0 + lz) * DD + kg * 1024;

    float4 wA[8], wB[8];
    #pragma unroll
    for (int e = 0; e < 8; ++e) wA[e] = *(const float4*)(Wb + e * DD);  // s0 g0

    for (int s = 0; s < 32; ++s) {
        if (s + 1 < 32) {
            const int nb = (s + 1) & 1;
            Xs[nb][sr][sdst+0] = xr.x; Xs[nb][sr][sdst+1] = xr.y;
            Xs[nb][sr][sdst+2] = xr.z; Xs[nb][sr][sdst+3] = xr.w;
            if (s + 2 < 32) xr = *(const float4*)(gX + (s + 2) * 32);
        }
        const float* xrow = &Xs[s & 1][lane][xoff];
        const float* Wst = Wb + s * 32;

        // 2-bank ping-pong: load group g+1 while FMA-ing group g
        #define LOADW(DST, OFF)                                             \
            _Pragma("unroll")                                               \
            for (int e = 0; e < 8; ++e)                                     \
                DST[e] = *(const float4*)(Wst + e * DD + (OFF));
        #define FMA8(WV, KC)                                                 \
            {                                                                \
                const float x0 = xrow[(KC)+0], x1 = xrow[(KC)+1];            \
                const float x2 = xrow[(KC)+2], x3 = xrow[(KC)+3];            \
                _Pragma("unroll")                                            \
                for (int e = 0; e < 8; ++e) {                                \
                    acc[e] = fmaf(x0, WV[e].x, acc[e]);                      \
                    acc[e] = fmaf(x1, WV[e].y, acc[e]);                      \
                    acc[e] = fmaf(x2, WV[e].z, acc[e]);                      \
                    acc[e] = fmaf(x3, WV[e].w, acc[e]);                      \
                }                                                            \
            }
        LOADW(wB, 4)   FMA8(wA, 0)
        LOADW(wA, 8)   FMA8(wB, 4)
        LOADW(wB, 12)  FMA8(wA, 8)
        LOADW(wA, 16)  FMA8(wB, 12)
        LOADW(wB, 20)  FMA8(wA, 16)
        LOADW(wA, 24)  FMA8(wB, 20)
        LOADW(wB, 28)  FMA8(wA, 24)
        if (s < 31) { LOADW(wA, 32) }
        FMA8(wB, 28)
        #undef LOADW
        #undef FMA8
        __syncthreads();
    }

    // combine K-halves in fixed order (half0 + half1), add bias
    if (tid < EE) cnt[tid] = 0;
    if (kg == 1) {
        *(float4*)&Ls[lane][we0 + 0] = make_float4(acc[0], acc[1], acc[2], acc[3]);
        *(float4*)&Ls[lane][we0 + 4] = make_float4(acc[4], acc[5], acc[6], acc[7]);
    }
    __syncthreads();
    if (kg == 0) {
        const float4 p0 = *(const float4*)&Ls[lane][we0 + 0];
        const float4 p1 = *(const float4*)&Ls[lane][we0 + 4];
        float f[8];
        f[0]=acc[0]+p0.x; f[1]=acc[1]+p0.y; f[2]=acc[2]+p0.z; f[3]=acc[3]+p0.w;
        f[4]=acc[4]+p1.x; f[5]=acc[5]+p1.y; f[6]=acc[6]+p1.z; f[7]=acc[7]+p1.w;
        #pragma unroll
        for (int e = 0; e < 8; ++e) f[e] += bias[we0 + e];
        *(float4*)&Ls[lane][we0 + 0] = make_float4(f[0], f[1], f[2], f[3]);
        *(float4*)&Ls[lane][we0 + 4] = make_float4(f[4], f[5], f[6], f[7]);
    }
    __syncthreads();

    // epilogue: 16 threads per token, 4 experts each
    const int tok = tid >> 4;
    const int o = tid & 15;
    const float4 vv = *(const float4*)&Ls[tok][o * 4];
    float v[4] = {vv.x, vv.y, vv.z, vv.w};

    float mx = fmaxf(fmaxf(v[0], v[1]), fmaxf(v[2], v[3]));
    #pragma unroll
    for (int sft = 1; sft < 16; sft <<= 1) mx = fmaxf(mx, __shfl_xor(mx, sft, 64));
    float sum = 0.f;
    #pragma unroll
    for (int j = 0; j < 4; ++j) sum += expf(v[j] - mx);
    #pragma unroll
    for (int sft = 1; sft < 16; sft <<= 1) sum += __shfl_xor(sum, sft, 64);
    const float lse = mx + logf(sum);

    float v1 = v[0]; int i1 = o * 4;
    float v2 = -3.402823466e38f; int i2 = 0x7fffffff;
    #pragma unroll
    for (int j = 1; j < 4; ++j) {
        const float vvj = v[j]; const int e = o * 4 + j;
        if (pair_gt(vvj, e, v1, i1)) { v2 = v1; i2 = i1; v1 = vvj; i1 = e; }
        else if (pair_gt(vvj, e, v2, i2)) { v2 = vvj; i2 = e; }
    }
    #pragma unroll
    for (int sft = 1; sft < 16; sft <<= 1) {
        const float ov1 = __shfl_xor(v1, sft, 64); const int oi1 = __shfl_xor(i1, sft, 64);
        const float ov2 = __shfl_xor(v2, sft, 64); const int oi2 = __shfl_xor(i2, sft, 64);
        if (pair_gt(ov1, oi1, v1, i1)) {
            if (pair_gt(v1, i1, ov2, oi2)) { v2 = v1; i2 = i1; }
            else                            { v2 = ov2; i2 = oi2; }
            v1 = ov1; i1 = oi1;
        } else {
            if (pair_gt(ov1, oi1, v2, i2)) { v2 = ov1; i2 = oi1; }
        }
    }

    if (o == 0) {
        lseS[tok] = lse;
        top2[tok0 + tok] = make_uint4((unsigned)i1, (unsigned)i2,
                                      __float_as_uint(expf(v1 - lse)),
                                      __float_as_uint(expf(v2 - lse)));
        atomicAdd(&cnt[i1], 1u);
        atomicAdd(&cnt[i2], 1u);
    }
    __syncthreads();

    // per-expert prob sums, fixed-order partials
    {
        const int e = tid & 63;
        const int tp = tid >> 6;               // 16 groups x 4 tokens
        float sme = 0.f;
        for (int t = tp * 4; t < tp * 4 + 4; ++t)
            sme += expf(Ls[t][e] - lseS[t]);
        ps2[tp][e] = sme;
    }
    __syncthreads();
    if (tid < EE) {
        float sacc = 0.f;
        #pragma unroll
        for (int p = 0; p < 16; ++p) sacc += ps2[p][tid];
        probsum[b * EE + tid] = sacc;
        counts[b * EE + tid] = cnt[tid];
    }
    if (tid == 0) {
        float z = 0.f;
        for (int t = 0; t < TM; ++t) z += lseS[t] * lseS[t];
        zsum[b] = z;
    }
}

// k2: per-expert exclusive prefix over 256 chunks (2-pass) + loss
__global__ __launch_bounds__(256) void k2_scan(
    const unsigned* __restrict__ counts, const float* __restrict__ probsum,
    const float* __restrict__ zsum, unsigned* __restrict__ base,
    float* __restrict__ loss_out)
{
    __shared__ unsigned pc[4][EE];
    __shared__ float pps[4][EE];
    __shared__ float zz[256];
    const int tid = threadIdx.x;
    const int e = tid & 63, q = tid >> 6;
    const int b0 = q * (NBLK / 4), b1 = b0 + (NBLK / 4);

    unsigned csum = 0; float psum_ = 0.f;
    for (int bb = b0; bb < b1; ++bb) {
        csum += counts[bb * EE + e];
        psum_ += probsum[bb * EE + e];
    }
    pc[q][e] = csum; pps[q][e] = psum_;
    zz[tid] = zsum[tid];
    __syncthreads();

    unsigned off = 0;
    for (int qq = 0; qq < q; ++qq) off += pc[qq][e];
    unsigned run = off;
    for (int bb = b0; bb < b1; ++bb) {
        base[bb * EE + e] = run;
        run += counts[bb * EE + e];
    }

    if (q == 0) {
        const unsigned tot = pc[0][e] + pc[1][e] + pc[2][e] + pc[3][e];
        const float pt = pps[0][e] + pps[1][e] + pps[2][e] + pps[3][e];
        float a = (float)tot * pt;
        #pragma unroll
        for (int sft = 1; sft < 64; sft <<= 1) a += __shfl_xor(a, sft, 64);
        float z4 = zz[tid] + zz[tid + 64] + zz[tid + 128] + zz[tid + 192];
        #pragma unroll
        for (int sft = 1; sft < 64; sft <<= 1) z4 += __shfl_xor(z4, sft, 64);
        if (e == 0) {
            const float Tf = (float)TT;
            loss_out[0] = 0.01f * 64.0f * (a / (Tf * Tf)) + z4 / Tf;
        }
    }
}

// k3: capacity ranking within each 64-token chunk + dense mask/weight writes
__global__ __launch_bounds__(256) void k3_write(
    const uint4* __restrict__ top2, const unsigned* __restrict__ base,
    float* __restrict__ mask_out, float* __restrict__ w_out)
{
    __shared__ unsigned ti1[TM], ti2[TM], tk1[TM], tk2[TM];
    __shared__ float tw1[TM], tw2[TM];
    const int b = blockIdx.x, tid = threadIdx.x;
    if (tid < TM) {
        const uint4 v = top2[b * TM + tid];
        ti1[tid] = v.x; ti2[tid] = v.y;
        tw1[tid] = __uint_as_float(v.z); tw2[tid] = __uint_as_float(v.w);
    }
    __syncthreads();
    if (tid < EE) {
        const unsigned e = (unsigned)tid;
        unsigned cc = base[b * EE + tid];
        for (int i = 0; i < TM; ++i) {   // token order = global cumsum order
            if (ti1[i] == e) { cc++; tk1[i] = (cc < CAP); }
            if (ti2[i] == e) { cc++; tk2[i] = (cc < CAP); }
        }
    }
    __syncthreads();
    const int i = tid >> 2, q = tid & 3;
    const unsigned a1 = ti1[i], a2 = ti2[i];
    const unsigned kp1 = tk1[i], kp2 = tk2[i];
    const float w1 = tw1[i], w2 = tw2[i];
    float om[16], ow[16];
    #pragma unroll
    for (int j = 0; j < 16; ++j) {
        const unsigned e = (unsigned)(q * 16 + j);
        float mv = 0.f, wv = 0.f;
        if (e == a1 && kp1) { mv = 1.f; wv = w1; }
        if (e == a2 && kp2) { mv = 1.f; wv = w2; }
        om[j] = mv; ow[j] = wv;
    }
    float* mrow = mask_out + (size_t)(b * TM + i) * EE + q * 16;
    float* wrow = w_out    + (size_t)(b * TM + i) * EE + q * 16;
    #pragma unroll
    for (int j4 = 0; j4 < 4; ++j4) {
        *(float4*)(mrow + j4 * 4) = make_float4(om[j4*4+0], om[j4*4+1], om[j4*4+2], om[j4*4+3]);
        *(float4*)(wrow + j4 * 4) = make_float4(ow[j4*4+0], ow[j4*4+1], ow[j4*4+2], ow[j4*4+3]);
    }
}

extern "C" void kernel_launch(void* const* d_in, const int* in_sizes, int n_in,
                              void* d_out, int out_size, void* d_ws, size_t ws_size,
                              hipStream_t stream)
{
    const float* X    = (const float*)d_in[0];
    const float* W    = (const float*)d_in[1];
    const float* bias = (const float*)d_in[2];
    float* out = (float*)d_out;
    float* mask_out = out;
    float* w_out    = out + (size_t)TT * EE;
    float* loss_out = out + (size_t)2 * TT * EE;

    char* ws = (char*)d_ws;
    uint4*    top2    = (uint4*)ws;                               // 256 KB
    unsigned* counts  = (unsigned*)(ws + 262144);                 // 64 KB
    float*    probsum = (float*)(ws + 262144 + 65536);            // 64 KB
    float*    zsum    = (float*)(ws + 262144 + 131072);           // 1 KB (pad 4K)
    unsigned* base    = (unsigned*)(ws + 262144 + 131072 + 4096); // 64 KB

    k1_router<<<NBLK, 1024, 0, stream>>>(X, W, bias, top2, counts, probsum, zsum);
    k2_scan<<<1, 256, 0, stream>>>(counts, probsum, zsum, base, loss_out);
    k3_write<<<NBLK, 256, 0, stream>>>(top2, base, mask_out, w_out);
}

// Round 5
// 126.149 us; speedup vs baseline: 2.6028x; 2.3163x over previous
//
#include <hip/hip_runtime.h>

#define TT 16384      // total tokens
#define DD 2048       // d_model
#define EE 64         // experts
#define KSPLIT 8
#define KSL (DD/KSPLIT)   // 256 k per split-block
#define TMA 256           // tokens per k1a block
#define NTB (TT/TMA)      // 64 token-blocks
#define TM 64             // tokens per stats chunk (k1b/k2/k3)
#define NBLK (TT/TM)      // 256
#define CAP 512u          // expert capacity (keep if 1-based position < CAP)

// workspace: partial 32MB + top2 256KB + stats ~200KB  (needs ~34MB ws)

__device__ __forceinline__ bool pair_gt(float va, int ia, float vb, int ib) {
    // jax.lax.top_k ordering: higher value wins; tie -> lower index wins
    return (va > vb) || (va == vb && ia < ib);
}

// k1a: partial gate GEMM. grid = NTB*KSPLIT, block = 512 (8 waves).
// Each lane: 4 tokens x 8 experts register tile (W float4 reused 4x -> VMEM
// instr rate 16:1 FMA:load, v3 was 4:1 and VMEM-issue-bound).
// X: global->LDS tile [256 tok][32 k], b64 XOR-swizzle pd = p ^ (t&15)
// (16-lane sweeps hit all 32 banks: conflict-free reads AND writes).
// W: per-lane VMEM broadcast (uniform addr laundered through LDS so the
// compiler can't re-scalarize to s_load); L1-resident (8KB/step).
__global__ __launch_bounds__(512) void k1a_gemm(
    const float* __restrict__ X, const float* __restrict__ W,
    float* __restrict__ partial)
{
    __shared__ float XsF[TMA * 32];   // [tok][32k], 8B-granular swizzled
    __shared__ int zt[1];

    const int tid = threadIdx.x;
    const int tb = blockIdx.x >> 3;
    const int sp = blockIdx.x & 7;
    const int tok0 = tb * TMA;
    const int kb = sp * KSL;
    const int l = tid & 63;
    const int w = tid >> 6;          // wave 0..7 = expert octet
    const int we0 = w * 8;

    if (tid == 0) zt[0] = 0;

    // staging map: thread -> (row r, half h); 2 threads cover a 128B row-chunk
    const int r = tid >> 1;
    const int hp = (tid & 1) * 8;    // dword-pair base (0 or 8)
    const int rsw = r & 15;
    const float* gX = X + (size_t)(tok0 + r) * DD + kb + hp * 2;

    float4 xr0 = *(const float4*)(gX + 0);
    float4 xr1 = *(const float4*)(gX + 4);
    float4 xr2 = *(const float4*)(gX + 8);
    float4 xr3 = *(const float4*)(gX + 12);

    __syncthreads();                 // zt visible; nothing else outstanding
    const int lz = zt[0];            // 0, but opaque -> VGPR addressing for W
    const float* Wb = W + (size_t)(we0 + lz) * DD + kb;

    float acc[4][8];
    #pragma unroll
    for (int q = 0; q < 4; ++q)
        #pragma unroll
        for (int e = 0; e < 8; ++e) acc[q][e] = 0.f;

    const int lsw = l & 15;          // == (l+64q)&15 for all q
    int rowb[4];
    #pragma unroll
    for (int q = 0; q < 4; ++q) rowb[q] = (l + 64 * q) * 32;

    for (int s = 0; s < 8; ++s) {
        // write staged chunk (swizzled b64 stores, conflict-free)
        {
            float2 xp[8] = {{xr0.x,xr0.y},{xr0.z,xr0.w},{xr1.x,xr1.y},{xr1.z,xr1.w},
                            {xr2.x,xr2.y},{xr2.z,xr2.w},{xr3.x,xr3.y},{xr3.z,xr3.w}};
            #pragma unroll
            for (int m = 0; m < 8; ++m) {
                const int pd = (hp + m) ^ rsw;
                *(float2*)&XsF[r * 32 + pd * 2] = xp[m];
            }
        }
        __syncthreads();             // tile ready
        if (s < 7) {                 // prefetch next step
            const float* gn = gX + (s + 1) * 32;
            xr0 = *(const float4*)(gn + 0);
            xr1 = *(const float4*)(gn + 4);
            xr2 = *(const float4*)(gn + 8);
            xr3 = *(const float4*)(gn + 12);
        }
        const float* Ws_ = Wb + s * 32;
        #pragma unroll
        for (int cc = 0; cc < 8; ++cc) {
            float4 wv[8];
            #pragma unroll
            for (int e = 0; e < 8; ++e)
                wv[e] = *(const float4*)(Ws_ + e * DD + cc * 4);
            float2 xa[4], xb[4];
            const int pa = ((cc * 2    ) ^ lsw) * 2;
            const int pb = ((cc * 2 + 1) ^ lsw) * 2;
            #pragma unroll
            for (int q = 0; q < 4; ++q) {
                xa[q] = *(const float2*)&XsF[rowb[q] + pa];
                xb[q] = *(const float2*)&XsF[rowb[q] + pb];
            }
            #pragma unroll
            for (int q = 0; q < 4; ++q) {
                #pragma unroll
                for (int e = 0; e < 8; ++e) {
                    acc[q][e] = fmaf(xa[q].x, wv[e].x, acc[q][e]);
                    acc[q][e] = fmaf(xa[q].y, wv[e].y, acc[q][e]);
                    acc[q][e] = fmaf(xb[q].x, wv[e].z, acc[q][e]);
                    acc[q][e] = fmaf(xb[q].y, wv[e].w, acc[q][e]);
                }
            }
        }
        __syncthreads();             // compute done before next overwrite
    }

    // writeout partials: [sp][tok][exp]
    #pragma unroll
    for (int q = 0; q < 4; ++q) {
        float* p = partial + ((size_t)sp * TT + tok0 + l + 64 * q) * EE + we0;
        *(float4*)(p + 0) = make_float4(acc[q][0], acc[q][1], acc[q][2], acc[q][3]);
        *(float4*)(p + 4) = make_float4(acc[q][4], acc[q][5], acc[q][6], acc[q][7]);
    }
}

// k1b: combine partials (fixed sp order) + bias + softmax + top2 + stats.
// grid = NBLK (64 tokens each), block = 512: 8 threads/token x 8 experts.
__global__ __launch_bounds__(512) void k1b_epilogue(
    const float* __restrict__ partial, const float* __restrict__ bias,
    uint4* __restrict__ top2, unsigned* __restrict__ counts,
    float* __restrict__ probsum, float* __restrict__ zsum)
{
    __shared__ float Es[TM][EE + 1];   // exp values, pad -> 2-way col reads
    __shared__ float lseS[TM];
    __shared__ unsigned cnt[EE];

    const int tid = threadIdx.x;
    const int b = blockIdx.x;
    const int tok0 = b * TM;
    const int tok = tid >> 3;
    const int o = tid & 7;
    const int e0 = o * 8;

    if (tid < EE) cnt[tid] = 0;
    __syncthreads();

    float f[8] = {0.f,0.f,0.f,0.f,0.f,0.f,0.f,0.f};
    #pragma unroll
    for (int sp = 0; sp < KSPLIT; ++sp) {
        const float* p = partial + ((size_t)sp * TT + tok0 + tok) * EE + e0;
        const float4 a = *(const float4*)(p);
        const float4 c = *(const float4*)(p + 4);
        f[0]+=a.x; f[1]+=a.y; f[2]+=a.z; f[3]+=a.w;
        f[4]+=c.x; f[5]+=c.y; f[6]+=c.z; f[7]+=c.w;
    }
    #pragma unroll
    for (int j = 0; j < 8; ++j) f[j] += bias[e0 + j];

    float mx = f[0];
    #pragma unroll
    for (int j = 1; j < 8; ++j) mx = fmaxf(mx, f[j]);
    #pragma unroll
    for (int sft = 1; sft < 8; sft <<= 1) mx = fmaxf(mx, __shfl_xor(mx, sft, 64));
    float sum = 0.f;
    #pragma unroll
    for (int j = 0; j < 8; ++j) sum += expf(f[j] - mx);
    #pragma unroll
    for (int sft = 1; sft < 8; sft <<= 1) sum += __shfl_xor(sum, sft, 64);
    const float lse = mx + logf(sum);

    float v1 = f[0]; int i1 = e0;
    float v2 = -3.402823466e38f; int i2 = 0x7fffffff;
    #pragma unroll
    for (int j = 1; j < 8; ++j) {
        const float vv = f[j]; const int e = e0 + j;
        if (pair_gt(vv, e, v1, i1)) { v2 = v1; i2 = i1; v1 = vv; i1 = e; }
        else if (pair_gt(vv, e, v2, i2)) { v2 = vv; i2 = e; }
    }
    #pragma unroll
    for (int sft = 1; sft < 8; sft <<= 1) {
        const float ov1 = __shfl_xor(v1, sft, 64); const int oi1 = __shfl_xor(i1, sft, 64);
        const float ov2 = __shfl_xor(v2, sft, 64); const int oi2 = __shfl_xor(i2, sft, 64);
        if (pair_gt(ov1, oi1, v1, i1)) {
            if (pair_gt(v1, i1, ov2, oi2)) { v2 = v1; i2 = i1; }
            else                            { v2 = ov2; i2 = oi2; }
            v1 = ov1; i1 = oi1;
        } else {
            if (pair_gt(ov1, oi1, v2, i2)) { v2 = ov1; i2 = oi1; }
        }
    }

    #pragma unroll
    for (int j = 0; j < 8; ++j) Es[tok][e0 + j] = expf(f[j] - lse);

    if (o == 0) {
        lseS[tok] = lse;
        top2[tok0 + tok] = make_uint4((unsigned)i1, (unsigned)i2,
                                      __float_as_uint(expf(v1 - lse)),
                                      __float_as_uint(expf(v2 - lse)));
        atomicAdd(&cnt[i1], 1u);
        atomicAdd(&cnt[i2], 1u);
    }
    __syncthreads();

    if (tid < EE) {
        float s = 0.f;
        for (int t = 0; t < TM; ++t) s += Es[t][tid];   // fixed order
        probsum[b * EE + tid] = s;
        counts[b * EE + tid] = cnt[tid];
    }
    if (tid >= 64 && tid < 128) {
        const int t = tid - 64;
        float z = lseS[t]; z = z * z;
        #pragma unroll
        for (int sft = 1; sft < 64; sft <<= 1) z += __shfl_xor(z, sft, 64);
        if (t == 0) zsum[b] = z;
    }
}

// k2: per-expert exclusive prefix over 256 chunks (2-pass) + loss
__global__ __launch_bounds__(256) void k2_scan(
    const unsigned* __restrict__ counts, const float* __restrict__ probsum,
    const float* __restrict__ zsum, unsigned* __restrict__ base,
    float* __restrict__ loss_out)
{
    __shared__ unsigned pc[4][EE];
    __shared__ float pps[4][EE];
    __shared__ float zz[256];
    const int tid = threadIdx.x;
    const int e = tid & 63, q = tid >> 6;
    const int b0 = q * (NBLK / 4), b1 = b0 + (NBLK / 4);

    unsigned csum = 0; float psum_ = 0.f;
    for (int bb = b0; bb < b1; ++bb) {
        csum += counts[bb * EE + e];
        psum_ += probsum[bb * EE + e];
    }
    pc[q][e] = csum; pps[q][e] = psum_;
    zz[tid] = zsum[tid];
    __syncthreads();

    unsigned off = 0;
    for (int qq = 0; qq < q; ++qq) off += pc[qq][e];
    unsigned run = off;
    for (int bb = b0; bb < b1; ++bb) {
        base[bb * EE + e] = run;
        run += counts[bb * EE + e];
    }

    if (q == 0) {
        const unsigned tot = pc[0][e] + pc[1][e] + pc[2][e] + pc[3][e];
        const float pt = pps[0][e] + pps[1][e] + pps[2][e] + pps[3][e];
        float a = (float)tot * pt;
        #pragma unroll
        for (int sft = 1; sft < 64; sft <<= 1) a += __shfl_xor(a, sft, 64);
        float z4 = zz[tid] + zz[tid + 64] + zz[tid + 128] + zz[tid + 192];
        #pragma unroll
        for (int sft = 1; sft < 64; sft <<= 1) z4 += __shfl_xor(z4, sft, 64);
        if (e == 0) {
            const float Tf = (float)TT;
            loss_out[0] = 0.01f * 64.0f * (a / (Tf * Tf)) + z4 / Tf;
        }
    }
}

// k3: capacity ranking within each 64-token chunk + dense mask/weight writes
__global__ __launch_bounds__(256) void k3_write(
    const uint4* __restrict__ top2, const unsigned* __restrict__ base,
    float* __restrict__ mask_out, float* __restrict__ w_out)
{
    __shared__ unsigned ti1[TM], ti2[TM], tk1[TM], tk2[TM];
    __shared__ float tw1[TM], tw2[TM];
    const int b = blockIdx.x, tid = threadIdx.x;
    if (tid < TM) {
        const uint4 v = top2[b * TM + tid];
        ti1[tid] = v.x; ti2[tid] = v.y;
        tw1[tid] = __uint_as_float(v.z); tw2[tid] = __uint_as_float(v.w);
    }
    __syncthreads();
    if (tid < EE) {
        const unsigned e = (unsigned)tid;
        unsigned cc = base[b * EE + tid];
        for (int i = 0; i < TM; ++i) {   // token order = global cumsum order
            if (ti1[i] == e) { cc++; tk1[i] = (cc < CAP); }
            if (ti2[i] == e) { cc++; tk2[i] = (cc < CAP); }
        }
    }
    __syncthreads();
    const int i = tid >> 2, q = tid & 3;
    const unsigned a1 = ti1[i], a2 = ti2[i];
    const unsigned kp1 = tk1[i], kp2 = tk2[i];
    const float w1 = tw1[i], w2 = tw2[i];
    float om[16], ow[16];
    #pragma unroll
    for (int j = 0; j < 16; ++j) {
        const unsigned e = (unsigned)(q * 16 + j);
        float mv = 0.f, wv = 0.f;
        if (e == a1 && kp1) { mv = 1.f; wv = w1; }
        if (e == a2 && kp2) { mv = 1.f; wv = w2; }
        om[j] = mv; ow[j] = wv;
    }
    float* mrow = mask_out + (size_t)(b * TM + i) * EE + q * 16;
    float* wrow = w_out    + (size_t)(b * TM + i) * EE + q * 16;
    #pragma unroll
    for (int j4 = 0; j4 < 4; ++j4) {
        *(float4*)(mrow + j4 * 4) = make_float4(om[j4*4+0], om[j4*4+1], om[j4*4+2], om[j4*4+3]);
        *(float4*)(wrow + j4 * 4) = make_float4(ow[j4*4+0], ow[j4*4+1], ow[j4*4+2], ow[j4*4+3]);
    }
}

extern "C" void kernel_launch(void* const* d_in, const int* in_sizes, int n_in,
                              void* d_out, int out_size, void* d_ws, size_t ws_size,
                              hipStream_t stream)
{
    const float* X    = (const float*)d_in[0];
    const float* W    = (const float*)d_in[1];
    const float* bias = (const float*)d_in[2];
    float* out = (float*)d_out;
    float* mask_out = out;
    float* w_out    = out + (size_t)TT * EE;
    float* loss_out = out + (size_t)2 * TT * EE;

    char* ws = (char*)d_ws;
    float*    partial = (float*)ws;                         // 32 MB
    size_t off = (size_t)KSPLIT * TT * EE * 4;              // 33,554,432
    uint4*    top2    = (uint4*)(ws + off);      off += (size_t)TT * 16;     // 256 KB
    unsigned* counts  = (unsigned*)(ws + off);   off += (size_t)NBLK * EE * 4;
    float*    probsum = (float*)(ws + off);      off += (size_t)NBLK * EE * 4;
    float*    zsum    = (float*)(ws + off);      off += 4096;
    unsigned* base    = (unsigned*)(ws + off);

    k1a_gemm<<<NTB * KSPLIT, 512, 0, stream>>>(X, W, partial);
    k1b_epilogue<<<NBLK, 512, 0, stream>>>(partial, bias, top2, counts, probsum, zsum);
    k2_scan<<<1, 256, 0, stream>>>(counts, probsum, zsum, base, loss_out);
    k3_write<<<NBLK, 256, 0, stream>>>(top2, base, mask_out, w_out);
}